// Round 1
// baseline (199.608 us; speedup 1.0000x reference)
//
#include <hip/hip_runtime.h>
#include <math.h>

constexpr int C  = 128;
constexpr int HH = 28;
constexpr int HW = 784;   // 28*28

// --- repack w2/a2 from [co][ci][kh][kw] to [k=kh*3+kw][ci][co] ---
__global__ __launch_bounds__(256) void reorder_w(const float* __restrict__ w2,
                                                 const float* __restrict__ a2,
                                                 float* __restrict__ w2r,
                                                 float* __restrict__ a2r) {
    int idx = blockIdx.x * 256 + threadIdx.x;
    const int total = C * C * 9;
    const float* src = w2;
    float* dst = w2r;
    if (idx >= total) { idx -= total; src = a2; dst = a2r; }
    if (idx >= total) return;
    int co = idx & 127;
    int ci = (idx >> 7) & 127;
    int k  = idx >> 14;               // 0..8
    dst[idx] = src[(co * C + ci) * 9 + k];
}

// --- stage 1: conv1x1 + adder1x1 + BN1 + ReLU -> t1 ---
// grid: 196 blocks (4 n * 49 tiles of 16 pixels), 256 threads
__global__ __launch_bounds__(256) void stage1(const float* __restrict__ x,
                                              const float* __restrict__ w1,
                                              const float* __restrict__ a1,
                                              const float* __restrict__ g1,
                                              const float* __restrict__ b1,
                                              const float* __restrict__ m1,
                                              const float* __restrict__ v1,
                                              float* __restrict__ t1) {
    __shared__ float Xs[16][132];     // [pixel][ci], padded stride
    int blk = blockIdx.x;
    int n  = blk / 49;
    int q0 = (blk % 49) * 16;
    int t  = threadIdx.x;
    int p  = t & 15;                  // pixel in tile
    int cob = (t >> 4) * 8;           // 8 output channels per thread

    const float* xn = x + n * C * HW;
    for (int e = t; e < 16 * C; e += 256) {
        int ci = e >> 4, pp = e & 15;
        Xs[pp][ci] = xn[ci * HW + q0 + pp];
    }
    __syncthreads();

    float acc[8];
#pragma unroll
    for (int j = 0; j < 8; ++j) acc[j] = 0.f;
    for (int ci = 0; ci < C; ci += 4) {
        float4 xv = *reinterpret_cast<const float4*>(&Xs[p][ci]);
#pragma unroll
        for (int j = 0; j < 8; ++j) {
            float4 wv = *reinterpret_cast<const float4*>(&w1[(cob + j) * C + ci]);
            acc[j] = fmaf(xv.x, wv.x, acc[j]);
            acc[j] = fmaf(xv.y, wv.y, acc[j]);
            acc[j] = fmaf(xv.z, wv.z, acc[j]);
            acc[j] = fmaf(xv.w, wv.w, acc[j]);
        }
    }
    __syncthreads();
    // write conv output back into the same LDS tile: Xs[p][co]
#pragma unroll
    for (int j = 0; j < 8; ++j) Xs[p][cob + j] = acc[j];
    __syncthreads();

#pragma unroll
    for (int j = 0; j < 8; ++j) acc[j] = 0.f;
    for (int ci = 0; ci < C; ci += 4) {
        float4 yv = *reinterpret_cast<const float4*>(&Xs[p][ci]);
#pragma unroll
        for (int j = 0; j < 8; ++j) {
            float4 av = *reinterpret_cast<const float4*>(&a1[(cob + j) * C + ci]);
            acc[j] += fabsf(yv.x - av.x) + fabsf(yv.y - av.y)
                    + fabsf(yv.z - av.z) + fabsf(yv.w - av.w);
        }
    }
#pragma unroll
    for (int j = 0; j < 8; ++j) {
        int co = cob + j;
        float inv = g1[co] / sqrtf(v1[co] + 1e-5f);
        float off = b1[co] - m1[co] * inv;
        float z = fmaxf(-acc[j] * inv + off, 0.f);
        t1[(n * C + co) * HW + q0 + p] = z;
    }
}

// --- stage 2: conv3x3 pad 1 -> t2 ---
// grid: 448 blocks = ((n*28 + h) * 4 + co_tile), 256 threads
__global__ __launch_bounds__(256) void conv3x3(const float* __restrict__ t1,
                                               const float* __restrict__ w2r,
                                               float* __restrict__ t2) {
    __shared__ float Xs[C][3][32];    // [ci][row][w+1], zero-padded halo
    int blk = blockIdx.x;
    int cot = blk & 3;
    int nh  = blk >> 2;
    int h   = nh % HH;
    int n   = nh / HH;
    int t   = threadIdx.x;
    int p   = t & 31;                 // output w, active p<28
    int pr  = p < 27 ? p : 27;        // clamp idle lanes
    int cog = t >> 5;
    int co0 = cot * 32 + cog * 4;

    float4* xs4 = reinterpret_cast<float4*>(&Xs[0][0][0]);
    for (int e = t; e < C * 3 * 32 / 4; e += 256) xs4[e] = make_float4(0.f, 0.f, 0.f, 0.f);
    __syncthreads();
    const float* src = t1 + n * C * HW;
    for (int e = t; e < C * 3 * 28; e += 256) {
        int ci  = e / 84;
        int rem = e - ci * 84;
        int r   = rem / 28;
        int w   = rem - r * 28;
        int hh  = h + r - 1;
        if ((unsigned)hh < 28u) Xs[ci][r][w + 1] = src[ci * HW + hh * 28 + w];
    }
    __syncthreads();

    float a0 = 0.f, a1 = 0.f, a2 = 0.f, a3 = 0.f;
    for (int ci = 0; ci < C; ++ci) {
#pragma unroll
        for (int kh = 0; kh < 3; ++kh) {
#pragma unroll
            for (int kw = 0; kw < 3; ++kw) {
                float xv = Xs[ci][kh][pr + kw];
                float4 wv = *reinterpret_cast<const float4*>(
                    &w2r[((kh * 3 + kw) * C + ci) * C + co0]);
                a0 = fmaf(xv, wv.x, a0);
                a1 = fmaf(xv, wv.y, a1);
                a2 = fmaf(xv, wv.z, a2);
                a3 = fmaf(xv, wv.w, a3);
            }
        }
    }
    if (p < 28) {
        float* dst = t2 + (n * C + co0) * HW + h * 28 + p;
        dst[0] = a0; dst[HW] = a1; dst[2 * HW] = a2; dst[3 * HW] = a3;
    }
}

// --- stage 3: adder3x3 pad 1 + BN2 + ReLU + residual + ReLU -> out ---
__global__ __launch_bounds__(256) void adder3x3(const float* __restrict__ t2,
                                                const float* __restrict__ a2r,
                                                const float* __restrict__ x0,
                                                const float* __restrict__ g2,
                                                const float* __restrict__ b2,
                                                const float* __restrict__ m2,
                                                const float* __restrict__ v2,
                                                float* __restrict__ out) {
    __shared__ float Xs[C][3][32];
    int blk = blockIdx.x;
    int cot = blk & 3;
    int nh  = blk >> 2;
    int h   = nh % HH;
    int n   = nh / HH;
    int t   = threadIdx.x;
    int p   = t & 31;
    int pr  = p < 27 ? p : 27;
    int cog = t >> 5;
    int co0 = cot * 32 + cog * 4;

    float4* xs4 = reinterpret_cast<float4*>(&Xs[0][0][0]);
    for (int e = t; e < C * 3 * 32 / 4; e += 256) xs4[e] = make_float4(0.f, 0.f, 0.f, 0.f);
    __syncthreads();
    const float* src = t2 + n * C * HW;
    for (int e = t; e < C * 3 * 28; e += 256) {
        int ci  = e / 84;
        int rem = e - ci * 84;
        int r   = rem / 28;
        int w   = rem - r * 28;
        int hh  = h + r - 1;
        if ((unsigned)hh < 28u) Xs[ci][r][w + 1] = src[ci * HW + hh * 28 + w];
    }
    __syncthreads();

    float acc[4] = {0.f, 0.f, 0.f, 0.f};
    for (int ci = 0; ci < C; ++ci) {
#pragma unroll
        for (int kh = 0; kh < 3; ++kh) {
#pragma unroll
            for (int kw = 0; kw < 3; ++kw) {
                float xv = Xs[ci][kh][pr + kw];
                float4 wv = *reinterpret_cast<const float4*>(
                    &a2r[((kh * 3 + kw) * C + ci) * C + co0]);
                acc[0] += fabsf(xv - wv.x);
                acc[1] += fabsf(xv - wv.y);
                acc[2] += fabsf(xv - wv.z);
                acc[3] += fabsf(xv - wv.w);
            }
        }
    }
    if (p < 28) {
        int base = (n * C + co0) * HW + h * 28 + p;
#pragma unroll
        for (int j = 0; j < 4; ++j) {
            int co = co0 + j;
            float inv = g2[co] / sqrtf(v2[co] + 1e-5f);
            float off = b2[co] - m2[co] * inv;
            float z = fmaxf(-acc[j] * inv + off, 0.f);
            z += x0[base + j * HW];
            out[base + j * HW] = fmaxf(z, 0.f);
        }
    }
}

extern "C" void kernel_launch(void* const* d_in, const int* in_sizes, int n_in,
                              void* d_out, int out_size, void* d_ws, size_t ws_size,
                              hipStream_t stream) {
    const float* x   = (const float*)d_in[0];
    const float* w1  = (const float*)d_in[1];   // w_shift1 (C,C,1,1)
    const float* a1  = (const float*)d_in[2];   // w_add1   (C,C,1,1)
    const float* g1  = (const float*)d_in[3];
    const float* b1  = (const float*)d_in[4];
    const float* m1  = (const float*)d_in[5];
    const float* v1  = (const float*)d_in[6];
    const float* w2  = (const float*)d_in[7];   // w_shift2 (C,C,3,3)
    const float* a2  = (const float*)d_in[8];   // w_add2   (C,C,3,3)
    const float* g2  = (const float*)d_in[9];
    const float* b2  = (const float*)d_in[10];
    const float* m2  = (const float*)d_in[11];
    const float* v2  = (const float*)d_in[12];
    float* out = (float*)d_out;

    float* ws  = (float*)d_ws;
    float* t1  = ws;                       // 401408
    float* t2  = t1 + 4 * C * HW;          // 401408
    float* w2r = t2 + 4 * C * HW;          // 147456
    float* a2r = w2r + C * C * 9;          // 147456

    const int reorder_total = 2 * C * C * 9;
    reorder_w<<<(reorder_total + 255) / 256, 256, 0, stream>>>(w2, a2, w2r, a2r);
    stage1<<<196, 256, 0, stream>>>(x, w1, a1, g1, b1, m1, v1, t1);
    conv3x3<<<448, 256, 0, stream>>>(t1, w2r, t2);
    adder3x3<<<448, 256, 0, stream>>>(t2, a2r, x, g2, b2, m2, v2, out);
}

// Round 2
// 172.711 us; speedup vs baseline: 1.1557x; 1.1557x over previous
//
#include <hip/hip_runtime.h>
#include <math.h>

constexpr int C  = 128;
constexpr int HH = 28;
constexpr int HW = 784;   // 28*28

// --- repack w2/a2 from [co][ci][kh][kw] to [k=kh*3+kw][ci][co] ---
__global__ __launch_bounds__(256) void reorder_w(const float* __restrict__ w2,
                                                 const float* __restrict__ a2,
                                                 float* __restrict__ w2r,
                                                 float* __restrict__ a2r) {
    int idx = blockIdx.x * 256 + threadIdx.x;
    const int total = C * C * 9;
    const float* src = w2;
    float* dst = w2r;
    if (idx >= total) { idx -= total; src = a2; dst = a2r; }
    if (idx >= total) return;
    int co = idx & 127;
    int ci = (idx >> 7) & 127;
    int k  = idx >> 14;               // 0..8
    dst[idx] = src[(co * C + ci) * 9 + k];
}

// --- stage 1: conv1x1 + adder1x1 + BN1 + ReLU -> t1 ---
// grid: 392 blocks (4 n * 98 tiles of 8 pixels), 512 threads
// thread = p(8) x cog(16, 8 co each) x ciq(4, 32 ci each)
__global__ __launch_bounds__(512, 4) void stage1(const float* __restrict__ x,
                                              const float* __restrict__ w1,
                                              const float* __restrict__ a1,
                                              const float* __restrict__ g1,
                                              const float* __restrict__ b1,
                                              const float* __restrict__ m1,
                                              const float* __restrict__ v1,
                                              float* __restrict__ t1) {
    __shared__ float Xs[8][132];          // [pixel][ci] then reused as [pixel][co]
    __shared__ float Rs[3][16][8][8];     // [ciq-1][cog][p][j]
    int blk = blockIdx.x;
    int n  = blk / 98;
    int q0 = (blk % 98) * 8;
    int t  = threadIdx.x;
    int p   = t & 7;
    int cog = (t >> 3) & 15;
    int ciq = t >> 7;                     // 0..3
    int cob = cog * 8;
    int ci0 = ciq * 32;

    const float* xn = x + n * C * HW;
    for (int e = t; e < 8 * C; e += 512) {
        int ci = e >> 3, pp = e & 7;
        Xs[pp][ci] = xn[ci * HW + q0 + pp];
    }
    __syncthreads();

    float acc[8];
#pragma unroll
    for (int j = 0; j < 8; ++j) acc[j] = 0.f;
    for (int ci = ci0; ci < ci0 + 32; ci += 4) {
        float4 xv = *reinterpret_cast<const float4*>(&Xs[p][ci]);
#pragma unroll
        for (int j = 0; j < 8; ++j) {
            float4 wv = *reinterpret_cast<const float4*>(&w1[(cob + j) * C + ci]);
            acc[j] = fmaf(xv.x, wv.x, acc[j]);
            acc[j] = fmaf(xv.y, wv.y, acc[j]);
            acc[j] = fmaf(xv.z, wv.z, acc[j]);
            acc[j] = fmaf(xv.w, wv.w, acc[j]);
        }
    }
    if (ciq) {
        *reinterpret_cast<float4*>(&Rs[ciq - 1][cog][p][0]) = make_float4(acc[0], acc[1], acc[2], acc[3]);
        *reinterpret_cast<float4*>(&Rs[ciq - 1][cog][p][4]) = make_float4(acc[4], acc[5], acc[6], acc[7]);
    }
    __syncthreads();                      // #1: conv partials ready, Xs reads done
    if (ciq == 0) {
#pragma unroll
        for (int q = 0; q < 3; ++q) {
            float4 r0 = *reinterpret_cast<const float4*>(&Rs[q][cog][p][0]);
            float4 r1 = *reinterpret_cast<const float4*>(&Rs[q][cog][p][4]);
            acc[0] += r0.x; acc[1] += r0.y; acc[2] += r0.z; acc[3] += r0.w;
            acc[4] += r1.x; acc[5] += r1.y; acc[6] += r1.z; acc[7] += r1.w;
        }
#pragma unroll
        for (int j = 0; j < 8; ++j) Xs[p][cob + j] = acc[j];  // conv output -> Xs
    }
    __syncthreads();                      // #2: conv output staged

    float ad[8];
#pragma unroll
    for (int j = 0; j < 8; ++j) ad[j] = 0.f;
    for (int ci = ci0; ci < ci0 + 32; ci += 4) {
        float4 yv = *reinterpret_cast<const float4*>(&Xs[p][ci]);
#pragma unroll
        for (int j = 0; j < 8; ++j) {
            float4 av = *reinterpret_cast<const float4*>(&a1[(cob + j) * C + ci]);
            ad[j] += fabsf(yv.x - av.x) + fabsf(yv.y - av.y)
                   + fabsf(yv.z - av.z) + fabsf(yv.w - av.w);
        }
    }
    if (ciq) {
        *reinterpret_cast<float4*>(&Rs[ciq - 1][cog][p][0]) = make_float4(ad[0], ad[1], ad[2], ad[3]);
        *reinterpret_cast<float4*>(&Rs[ciq - 1][cog][p][4]) = make_float4(ad[4], ad[5], ad[6], ad[7]);
    }
    __syncthreads();                      // #3: adder partials ready
    if (ciq == 0) {
#pragma unroll
        for (int q = 0; q < 3; ++q) {
            float4 r0 = *reinterpret_cast<const float4*>(&Rs[q][cog][p][0]);
            float4 r1 = *reinterpret_cast<const float4*>(&Rs[q][cog][p][4]);
            ad[0] += r0.x; ad[1] += r0.y; ad[2] += r0.z; ad[3] += r0.w;
            ad[4] += r1.x; ad[5] += r1.y; ad[6] += r1.z; ad[7] += r1.w;
        }
#pragma unroll
        for (int j = 0; j < 8; ++j) {
            int co = cob + j;
            float inv = g1[co] / sqrtf(v1[co] + 1e-5f);
            float off = b1[co] - m1[co] * inv;
            float z = fmaxf(-ad[j] * inv + off, 0.f);
            t1[(n * C + co) * HW + q0 + p] = z;
        }
    }
}

// --- stage 2: conv3x3 pad 1 -> t2 ---
// grid: 448 blocks = ((n*28 + h) * 4 + co_tile), 1024 threads
// thread = p(32) x cog(8, 4 co each) x ciq(4, 32 ci each)
__global__ __launch_bounds__(1024, 8) void conv3x3(const float* __restrict__ t1,
                                               const float* __restrict__ w2r,
                                               float* __restrict__ t2) {
    __shared__ float Xs[C][3][32];    // [ci][row][w+1], zero-padded halo (48KB)
    __shared__ float Rs[3][8][32][4]; // partials from ciq 1..3 (12KB)
    int blk = blockIdx.x;
    int cot = blk & 3;
    int nh  = blk >> 2;
    int h   = nh % HH;
    int n   = nh / HH;
    int t   = threadIdx.x;
    int p   = t & 31;                 // output w, active p<28
    int pr  = p < 27 ? p : 27;        // clamp idle lanes
    int cog = (t >> 5) & 7;
    int ciq = t >> 8;                 // 0..3
    int co0 = cot * 32 + cog * 4;
    int ci0 = ciq * 32;

    float4* xs4 = reinterpret_cast<float4*>(&Xs[0][0][0]);
    for (int e = t; e < C * 3 * 32 / 4; e += 1024) xs4[e] = make_float4(0.f, 0.f, 0.f, 0.f);
    __syncthreads();
    const float* src = t1 + n * C * HW;
    for (int e = t; e < C * 3 * 28; e += 1024) {
        int ci  = e / 84;
        int rem = e - ci * 84;
        int r   = rem / 28;
        int w   = rem - r * 28;
        int hh  = h + r - 1;
        if ((unsigned)hh < 28u) Xs[ci][r][w + 1] = src[ci * HW + hh * 28 + w];
    }
    __syncthreads();

    float a0 = 0.f, a1 = 0.f, a2 = 0.f, a3 = 0.f;
    for (int ci = ci0; ci < ci0 + 32; ++ci) {
#pragma unroll
        for (int kh = 0; kh < 3; ++kh) {
#pragma unroll
            for (int kw = 0; kw < 3; ++kw) {
                float xv = Xs[ci][kh][pr + kw];
                float4 wv = *reinterpret_cast<const float4*>(
                    &w2r[((kh * 3 + kw) * C + ci) * C + co0]);
                a0 = fmaf(xv, wv.x, a0);
                a1 = fmaf(xv, wv.y, a1);
                a2 = fmaf(xv, wv.z, a2);
                a3 = fmaf(xv, wv.w, a3);
            }
        }
    }
    if (ciq) *reinterpret_cast<float4*>(&Rs[ciq - 1][cog][p][0]) = make_float4(a0, a1, a2, a3);
    __syncthreads();
    if (ciq == 0 && p < 28) {
#pragma unroll
        for (int q = 0; q < 3; ++q) {
            float4 r = *reinterpret_cast<const float4*>(&Rs[q][cog][p][0]);
            a0 += r.x; a1 += r.y; a2 += r.z; a3 += r.w;
        }
        float* dst = t2 + (n * C + co0) * HW + h * 28 + p;
        dst[0] = a0; dst[HW] = a1; dst[2 * HW] = a2; dst[3 * HW] = a3;
    }
}

// --- stage 3: adder3x3 pad 1 + BN2 + ReLU + residual + ReLU -> out ---
__global__ __launch_bounds__(1024, 8) void adder3x3(const float* __restrict__ t2,
                                                const float* __restrict__ a2r,
                                                const float* __restrict__ x0,
                                                const float* __restrict__ g2,
                                                const float* __restrict__ b2,
                                                const float* __restrict__ m2,
                                                const float* __restrict__ v2,
                                                float* __restrict__ out) {
    __shared__ float Xs[C][3][32];
    __shared__ float Rs[3][8][32][4];
    int blk = blockIdx.x;
    int cot = blk & 3;
    int nh  = blk >> 2;
    int h   = nh % HH;
    int n   = nh / HH;
    int t   = threadIdx.x;
    int p   = t & 31;
    int pr  = p < 27 ? p : 27;
    int cog = (t >> 5) & 7;
    int ciq = t >> 8;
    int co0 = cot * 32 + cog * 4;
    int ci0 = ciq * 32;

    float4* xs4 = reinterpret_cast<float4*>(&Xs[0][0][0]);
    for (int e = t; e < C * 3 * 32 / 4; e += 1024) xs4[e] = make_float4(0.f, 0.f, 0.f, 0.f);
    __syncthreads();
    const float* src = t2 + n * C * HW;
    for (int e = t; e < C * 3 * 28; e += 1024) {
        int ci  = e / 84;
        int rem = e - ci * 84;
        int r   = rem / 28;
        int w   = rem - r * 28;
        int hh  = h + r - 1;
        if ((unsigned)hh < 28u) Xs[ci][r][w + 1] = src[ci * HW + hh * 28 + w];
    }
    __syncthreads();

    float acc[4] = {0.f, 0.f, 0.f, 0.f};
    for (int ci = ci0; ci < ci0 + 32; ++ci) {
#pragma unroll
        for (int kh = 0; kh < 3; ++kh) {
#pragma unroll
            for (int kw = 0; kw < 3; ++kw) {
                float xv = Xs[ci][kh][pr + kw];
                float4 wv = *reinterpret_cast<const float4*>(
                    &a2r[((kh * 3 + kw) * C + ci) * C + co0]);
                acc[0] += fabsf(xv - wv.x);
                acc[1] += fabsf(xv - wv.y);
                acc[2] += fabsf(xv - wv.z);
                acc[3] += fabsf(xv - wv.w);
            }
        }
    }
    if (ciq) *reinterpret_cast<float4*>(&Rs[ciq - 1][cog][p][0]) = make_float4(acc[0], acc[1], acc[2], acc[3]);
    __syncthreads();
    if (ciq == 0 && p < 28) {
#pragma unroll
        for (int q = 0; q < 3; ++q) {
            float4 r = *reinterpret_cast<const float4*>(&Rs[q][cog][p][0]);
            acc[0] += r.x; acc[1] += r.y; acc[2] += r.z; acc[3] += r.w;
        }
        int base = (n * C + co0) * HW + h * 28 + p;
#pragma unroll
        for (int j = 0; j < 4; ++j) {
            int co = co0 + j;
            float inv = g2[co] / sqrtf(v2[co] + 1e-5f);
            float off = b2[co] - m2[co] * inv;
            float z = fmaxf(-acc[j] * inv + off, 0.f);
            z += x0[base + j * HW];
            out[base + j * HW] = fmaxf(z, 0.f);
        }
    }
}

extern "C" void kernel_launch(void* const* d_in, const int* in_sizes, int n_in,
                              void* d_out, int out_size, void* d_ws, size_t ws_size,
                              hipStream_t stream) {
    const float* x   = (const float*)d_in[0];
    const float* w1  = (const float*)d_in[1];   // w_shift1 (C,C,1,1)
    const float* a1  = (const float*)d_in[2];   // w_add1   (C,C,1,1)
    const float* g1  = (const float*)d_in[3];
    const float* b1  = (const float*)d_in[4];
    const float* m1  = (const float*)d_in[5];
    const float* v1  = (const float*)d_in[6];
    const float* w2  = (const float*)d_in[7];   // w_shift2 (C,C,3,3)
    const float* a2  = (const float*)d_in[8];   // w_add2   (C,C,3,3)
    const float* g2  = (const float*)d_in[9];
    const float* b2  = (const float*)d_in[10];
    const float* m2  = (const float*)d_in[11];
    const float* v2  = (const float*)d_in[12];
    float* out = (float*)d_out;

    float* ws  = (float*)d_ws;
    float* t1  = ws;                       // 401408
    float* t2  = t1 + 4 * C * HW;          // 401408
    float* w2r = t2 + 4 * C * HW;          // 147456
    float* a2r = w2r + C * C * 9;          // 147456

    const int reorder_total = 2 * C * C * 9;
    reorder_w<<<(reorder_total + 255) / 256, 256, 0, stream>>>(w2, a2, w2r, a2r);
    stage1<<<392, 512, 0, stream>>>(x, w1, a1, g1, b1, m1, v1, t1);
    conv3x3<<<448, 1024, 0, stream>>>(t1, w2r, t2);
    adder3x3<<<448, 1024, 0, stream>>>(t2, a2r, x, g2, b2, m2, v2, out);
}